// Round 1
// baseline (1307.046 us; speedup 1.0000x reference)
//
#include <hip/hip_runtime.h>
#include <hip/hip_bf16.h>

// GCN link-prediction net, algebraically collapsed:
//   h1 = x @ W1                         (only real GEMM, fp32 vector ALU)
//   g[n] = relu(agg(h1)[n] + b1) . (W2 @ score_w)   (layer2 GEMM eliminated)
//   hw[n] = scalar-agg(g)               (b2 cancels in dist = h[j]-h[i])
//   out[e] = relu(hw[src]-hw[dst] + sb); loss = mean(hw[src]-hw[dst])

#define F_IN 512
#define F_H  128
#define F_C  64

// ---------------- CSR build ----------------

__global__ void count_kernel(const int* __restrict__ col, int E, int* __restrict__ cnt) {
    int stride = gridDim.x * blockDim.x;
    for (int e = blockIdx.x * blockDim.x + threadIdx.x; e < E; e += stride)
        atomicAdd(&cnt[col[e]], 1);
}

__global__ void dinv_kernel(const int* __restrict__ cnt, float* __restrict__ dinv, int N) {
    int i = blockIdx.x * blockDim.x + threadIdx.x;
    if (i < N) {
        float deg = (float)cnt[i] + 1.0f;   // +1 self loop
        dinv[i] = 1.0f / sqrtf(deg);
    }
}

// single-block exclusive scan over cnt -> offs[0..N], cursor = offs copy
__global__ void scan_kernel(const int* __restrict__ cnt, int* __restrict__ offs,
                            int* __restrict__ cursor, int N) {
    __shared__ int smem[1024];
    __shared__ int s_carry;
    if (threadIdx.x == 0) s_carry = 0;
    __syncthreads();
    for (int base = 0; base < N; base += 1024) {
        int i = base + (int)threadIdx.x;
        int v = (i < N) ? cnt[i] : 0;
        smem[threadIdx.x] = v;
        __syncthreads();
        for (int d = 1; d < 1024; d <<= 1) {
            int t = (threadIdx.x >= (unsigned)d) ? smem[threadIdx.x - d] : 0;
            __syncthreads();
            smem[threadIdx.x] += t;
            __syncthreads();
        }
        int carry = s_carry;
        int excl = carry + smem[threadIdx.x] - v;
        if (i < N) { offs[i] = excl; cursor[i] = excl; }
        __syncthreads();
        if (threadIdx.x == 0) s_carry = carry + smem[1023];
        __syncthreads();
    }
    if (threadIdx.x == 0) offs[N] = s_carry;
}

__global__ void fill_kernel(const int* __restrict__ ei, int E, int* __restrict__ cursor,
                            const float* __restrict__ dinv,
                            int* __restrict__ csr_src, float* __restrict__ csr_norm) {
    int stride = gridDim.x * blockDim.x;
    for (int e = blockIdx.x * blockDim.x + threadIdx.x; e < E; e += stride) {
        int r = ei[e];          // source
        int c = ei[E + e];      // target
        int idx = atomicAdd(&cursor[c], 1);
        csr_src[idx] = r;
        csr_norm[idx] = dinv[r] * dinv[c];
    }
}

// ---------------- w2v = W2 @ score_w ----------------

__global__ void w2v_kernel(const float* __restrict__ W2, const float* __restrict__ sw,
                           float* __restrict__ w2v) {
    int k = threadIdx.x;    // 128 threads
    if (k < F_H) {
        float acc = 0.0f;
        #pragma unroll
        for (int c = 0; c < F_C; ++c) acc += W2[k * F_C + c] * sw[c];
        w2v[k] = acc;
    }
}

// ---------------- GEMM1: C[N,128] = X[N,512] @ W[512,128] ----------------
// 256 threads, 32 rows/block; cg = tid&31 -> cols 4cg..4cg+3; rg = tid>>5 -> rows 4rg..4rg+3

__global__ __launch_bounds__(256) void gemm1_kernel(const float* __restrict__ X,
                                                    const float* __restrict__ W,
                                                    float* __restrict__ C, int N) {
    __shared__ __align__(16) float xs[32][36];   // [k][row], padded, 16B-aligned rows
    __shared__ __align__(16) float wl[32][128];  // [k][col]
    int tid = threadIdx.x;
    int cg = tid & 31, rg = tid >> 5;
    int brow = blockIdx.x * 32;
    float acc[4][4] = {};
    for (int k0 = 0; k0 < F_IN; k0 += 32) {
        // stage X tile transposed
        {
            int r = tid >> 3;
            int kq = (tid & 7) * 4;
            int row = brow + r; if (row >= N) row = N - 1;
            float4 v = *(const float4*)(X + (size_t)row * F_IN + k0 + kq);
            xs[kq + 0][r] = v.x; xs[kq + 1][r] = v.y;
            xs[kq + 2][r] = v.z; xs[kq + 3][r] = v.w;
        }
        // stage W tile
        {
            int c4 = (tid & 31) * 4, kr = tid >> 5;
            #pragma unroll
            for (int kk = 0; kk < 4; ++kk) {
                int k = kr + kk * 8;
                *(float4*)&wl[k][c4] = *(const float4*)(W + (size_t)(k0 + k) * F_H + c4);
            }
        }
        __syncthreads();
        #pragma unroll
        for (int k = 0; k < 32; ++k) {
            float4 xv = *(const float4*)&xs[k][rg * 4];
            float4 wv = *(const float4*)&wl[k][cg * 4];
            float xr[4] = {xv.x, xv.y, xv.z, xv.w};
            float wc[4] = {wv.x, wv.y, wv.z, wv.w};
            #pragma unroll
            for (int a = 0; a < 4; ++a)
                #pragma unroll
                for (int b = 0; b < 4; ++b)
                    acc[a][b] = fmaf(xr[a], wc[b], acc[a][b]);
        }
        __syncthreads();
    }
    #pragma unroll
    for (int r = 0; r < 4; ++r) {
        int row = brow + rg * 4 + r;
        if (row < N) {
            float4 v = {acc[r][0], acc[r][1], acc[r][2], acc[r][3]};
            *(float4*)(C + (size_t)row * F_H + cg * 4) = v;
        }
    }
}

// ---------------- agg1 + relu + dot(w2v) -> g ----------------
// one wave (64 lanes) per node; lane holds 2 features (float2)

__global__ __launch_bounds__(256) void agg1_g_kernel(
        const float* __restrict__ h1, const int* __restrict__ offs,
        const int* __restrict__ csr_src, const float* __restrict__ csr_norm,
        const float* __restrict__ dinv, const float* __restrict__ b1,
        const float* __restrict__ w2v, float* __restrict__ g, int N) {
    int gw = (int)((blockIdx.x * blockDim.x + threadIdx.x) >> 6);
    int lane = threadIdx.x & 63;
    if (gw >= N) return;
    int node = gw;
    float di = dinv[node];
    float sw = di * di;
    float2 hv = *(const float2*)(h1 + (size_t)node * F_H + lane * 2);
    float ax = hv.x * sw, ay = hv.y * sw;
    int s = offs[node], e = offs[node + 1];
    for (int i = s; i < e; ++i) {
        int src = csr_src[i];
        float nw = csr_norm[i];
        float2 v = *(const float2*)(h1 + (size_t)src * F_H + lane * 2);
        ax = fmaf(v.x, nw, ax);
        ay = fmaf(v.y, nw, ay);
    }
    float2 bv = *(const float2*)(b1 + lane * 2);
    ax = fmaxf(ax + bv.x, 0.0f);
    ay = fmaxf(ay + bv.y, 0.0f);
    float2 wv = *(const float2*)(w2v + lane * 2);
    float v = ax * wv.x + ay * wv.y;
    #pragma unroll
    for (int off = 32; off; off >>= 1) v += __shfl_xor(v, off, 64);
    if (lane == 0) g[node] = v;
}

// ---------------- scalar aggregation: hw[n] ----------------

__global__ void agg_s_kernel(const float* __restrict__ g, const int* __restrict__ offs,
                             const int* __restrict__ csr_src, const float* __restrict__ csr_norm,
                             const float* __restrict__ dinv, float* __restrict__ hw, int N) {
    int i = blockIdx.x * blockDim.x + threadIdx.x;
    if (i >= N) return;
    float di = dinv[i];
    float acc = g[i] * di * di;
    int s = offs[i], e = offs[i + 1];
    for (int j = s; j < e; ++j)
        acc = fmaf(csr_norm[j], g[csr_src[j]], acc);
    hw[i] = acc;
}

// ---------------- per-edge scoring ----------------

__global__ __launch_bounds__(256) void score_kernel(
        const float* __restrict__ hw, const int* __restrict__ pos_ei,
        const int* __restrict__ neg_ei, int Ep, const float* __restrict__ score_b,
        float* __restrict__ out, float* __restrict__ partials) {
    __shared__ float sdata[256];
    int Etot = 2 * Ep;
    int idx = blockIdx.x * 256 + threadIdx.x;
    float local = 0.0f;
    if (idx < Etot) {
        int src, dst;
        if (idx < Ep) { src = pos_ei[idx];       dst = pos_ei[Ep + idx]; }
        else          { int e = idx - Ep; src = neg_ei[e]; dst = neg_ei[Ep + e]; }
        float s = hw[src] - hw[dst];
        out[idx] = fmaxf(s + score_b[0], 0.0f);
        local = s;
    }
    sdata[threadIdx.x] = local;
    __syncthreads();
    for (int d = 128; d; d >>= 1) {
        if ((int)threadIdx.x < d) sdata[threadIdx.x] += sdata[threadIdx.x + d];
        __syncthreads();
    }
    if (threadIdx.x == 0) partials[blockIdx.x] = sdata[0];
}

__global__ void loss_final_kernel(const float* __restrict__ partials, int n,
                                  float* __restrict__ loss_out, float inv) {
    __shared__ float sdata[256];
    float local = 0.0f;
    for (int i = threadIdx.x; i < n; i += 256) local += partials[i];
    sdata[threadIdx.x] = local;
    __syncthreads();
    for (int d = 128; d; d >>= 1) {
        if ((int)threadIdx.x < d) sdata[threadIdx.x] += sdata[threadIdx.x + d];
        __syncthreads();
    }
    if (threadIdx.x == 0) *loss_out = sdata[0] * inv;
}

// ---------------- launch ----------------

extern "C" void kernel_launch(void* const* d_in, const int* in_sizes, int n_in,
                              void* d_out, int out_size, void* d_ws, size_t ws_size,
                              hipStream_t stream) {
    const float* x        = (const float*)d_in[0];
    const int*   edge     = (const int*)d_in[1];
    const int*   pos_ei   = (const int*)d_in[2];
    const int*   neg_ei   = (const int*)d_in[3];
    const float* W1       = (const float*)d_in[4];
    // d_in[5] = b1, d_in[6] = W2, d_in[7] = b2 (cancels), d_in[8] = score_w, d_in[9] = score_b
    const float* b1       = (const float*)d_in[5];
    const float* W2       = (const float*)d_in[6];
    const float* score_w  = (const float*)d_in[8];
    const float* score_b  = (const float*)d_in[9];

    int N    = in_sizes[0] / F_IN;   // 100000
    int E    = in_sizes[1] / 2;      // 3.2M
    int Ep   = in_sizes[2] / 2;      // 500k
    int Etot = 2 * Ep;               // 1M
    float* out = (float*)d_out;      // [Etot] scores then [1] loss

    // workspace carve (256B aligned), ~79 MB total
    char* p = (char*)d_ws;
    auto alloc = [&](size_t bytes) { char* r = p; p += (bytes + 255) & ~(size_t)255; return r; };
    int*   cnt      = (int*)  alloc((size_t)N * 4);
    int*   offs     = (int*)  alloc((size_t)(N + 1) * 4);
    int*   cursor   = (int*)  alloc((size_t)N * 4);
    float* dinv     = (float*)alloc((size_t)N * 4);
    float* gbuf     = (float*)alloc((size_t)N * 4);
    float* hw       = (float*)alloc((size_t)N * 4);
    float* w2v      = (float*)alloc(F_H * 4);
    int*   csr_src  = (int*)  alloc((size_t)E * 4);
    float* csr_norm = (float*)alloc((size_t)E * 4);
    float* h1       = (float*)alloc((size_t)N * F_H * 4);
    int sblk = (Etot + 255) / 256;
    float* partials = (float*)alloc((size_t)sblk * 4);

    hipMemsetAsync(cnt, 0, (size_t)N * 4, stream);
    count_kernel<<<2048, 256, 0, stream>>>(edge + E, E, cnt);
    dinv_kernel<<<(N + 255) / 256, 256, 0, stream>>>(cnt, dinv, N);
    scan_kernel<<<1, 1024, 0, stream>>>(cnt, offs, cursor, N);
    fill_kernel<<<2048, 256, 0, stream>>>(edge, E, cursor, dinv, csr_src, csr_norm);
    w2v_kernel<<<1, 128, 0, stream>>>(W2, score_w, w2v);
    gemm1_kernel<<<(N + 31) / 32, 256, 0, stream>>>(x, W1, h1, N);
    agg1_g_kernel<<<(N * 64 + 255) / 256, 256, 0, stream>>>(h1, offs, csr_src, csr_norm,
                                                            dinv, b1, w2v, gbuf, N);
    agg_s_kernel<<<(N + 255) / 256, 256, 0, stream>>>(gbuf, offs, csr_src, csr_norm,
                                                      dinv, hw, N);
    score_kernel<<<sblk, 256, 0, stream>>>(hw, pos_ei, neg_ei, Ep, score_b, out, partials);
    loss_final_kernel<<<1, 256, 0, stream>>>(partials, sblk, out + Etot, 1.0f / (float)Etot);
}

// Round 2
// 841.604 us; speedup vs baseline: 1.5530x; 1.5530x over previous
//
#include <hip/hip_runtime.h>
#include <hip/hip_bf16.h>

// GCN link-prediction net, algebraically collapsed:
//   h1 = x @ W1                  (bf16 MFMA, fp32 accum)
//   g[n] = relu(agg(h1)[n] + b1) . (W2 @ score_w)   (layer2 GEMM eliminated)
//   hw[n] = scalar-agg(g)        (b2 cancels in dist = h[j]-h[i])
//   out[e] = relu(hw[src]-hw[dst] + sb); loss = mean(hw[src]-hw[dst])

#define F_IN 512
#define F_H  128
#define F_C  64

typedef __attribute__((ext_vector_type(8))) short short8;
typedef __attribute__((ext_vector_type(4))) float f32x4;

__device__ __forceinline__ ushort f2bf(float f) {
    uint u = __float_as_uint(f);
    uint r = (u + 0x7fffu + ((u >> 16) & 1u)) >> 16;   // RNE
    return (ushort)r;
}
__device__ __forceinline__ float bflo(uint v) { return __uint_as_float(v << 16); }
__device__ __forceinline__ float bfhi(uint v) { return __uint_as_float(v & 0xffff0000u); }

// ---------------- CSR build ----------------

__global__ void count_kernel(const int* __restrict__ col, int E, int* __restrict__ cnt) {
    int stride = gridDim.x * blockDim.x;
    for (int e = blockIdx.x * blockDim.x + threadIdx.x; e < E; e += stride)
        atomicAdd(&cnt[col[e]], 1);
}

__global__ void dinv_kernel(const int* __restrict__ cnt, float* __restrict__ dinv, int N) {
    int i = blockIdx.x * blockDim.x + threadIdx.x;
    if (i < N) {
        float deg = (float)cnt[i] + 1.0f;   // +1 self loop
        dinv[i] = 1.0f / sqrtf(deg);
    }
}

// hierarchical scan: per-block sums -> tiny serial scan -> per-block scan
__global__ __launch_bounds__(1024) void bsum_kernel(const int* __restrict__ cnt,
                                                    int* __restrict__ bsum, int N) {
    __shared__ int sm[1024];
    int i = blockIdx.x * 1024 + threadIdx.x;
    sm[threadIdx.x] = (i < N) ? cnt[i] : 0;
    __syncthreads();
    for (int d = 512; d; d >>= 1) {
        if ((int)threadIdx.x < d) sm[threadIdx.x] += sm[threadIdx.x + d];
        __syncthreads();
    }
    if (threadIdx.x == 0) bsum[blockIdx.x] = sm[0];
}

__global__ void bscan_kernel(int* __restrict__ bsum, int nb) {
    if (threadIdx.x == 0 && blockIdx.x == 0) {
        int run = 0;
        for (int b = 0; b < nb; ++b) { int v = bsum[b]; bsum[b] = run; run += v; }
    }
}

__global__ __launch_bounds__(1024) void offs_kernel(const int* __restrict__ cnt,
                                                    const int* __restrict__ boffs,
                                                    int* __restrict__ offs,
                                                    int* __restrict__ cursor, int N) {
    __shared__ int sm[1024];
    int i = blockIdx.x * 1024 + threadIdx.x;
    int v = (i < N) ? cnt[i] : 0;
    sm[threadIdx.x] = v;
    __syncthreads();
    for (int d = 1; d < 1024; d <<= 1) {
        int t = ((int)threadIdx.x >= d) ? sm[threadIdx.x - d] : 0;
        __syncthreads();
        sm[threadIdx.x] += t;
        __syncthreads();
    }
    int incl = sm[threadIdx.x];
    int base = boffs[blockIdx.x];
    if (i < N) {
        int ex = base + incl - v;
        offs[i] = ex; cursor[i] = ex;
        if (i == N - 1) offs[N] = base + incl;
    }
}

__global__ void fill_kernel(const int* __restrict__ ei, int E, int* __restrict__ cursor,
                            const float* __restrict__ dinv, int2* __restrict__ csr) {
    int stride = gridDim.x * blockDim.x;
    for (int e = blockIdx.x * blockDim.x + threadIdx.x; e < E; e += stride) {
        int r = ei[e];          // source
        int c = ei[E + e];      // target
        int idx = atomicAdd(&cursor[c], 1);
        int2 v; v.x = r; v.y = __float_as_int(dinv[r] * dinv[c]);
        csr[idx] = v;
    }
}

// ---------------- tiny weight prep ----------------

__global__ void w2v_kernel(const float* __restrict__ W2, const float* __restrict__ sw,
                           float* __restrict__ w2v) {
    int k = threadIdx.x;
    if (k < F_H) {
        float acc = 0.0f;
        #pragma unroll
        for (int c = 0; c < F_C; ++c) acc += W2[k * F_C + c] * sw[c];
        w2v[k] = acc;
    }
}

// W_T[c][k] = bf16(W1[k][c])
__global__ void wt_kernel(const float* __restrict__ W, ushort* __restrict__ WT) {
    int i = blockIdx.x * 256 + threadIdx.x;
    if (i < F_IN * F_H) {
        int k = i >> 7, c = i & 127;
        WT[c * F_IN + k] = f2bf(W[i]);
    }
}

// ---------------- GEMM1 via MFMA: H[N,128] (bf16) = X[N,512] @ W1 ----------------
// block = 256 thr = 4 waves; tile 32 rows x 128 cols; wave w: rows (w&1)*16, cols (w>>1)*64

__global__ __launch_bounds__(256) void gemm1_mfma(const float* __restrict__ X,
                                                  const ushort* __restrict__ WT,
                                                  ushort* __restrict__ H, int N) {
    int tid = threadIdx.x;
    int w = tid >> 6, l = tid & 63;
    int brow = blockIdx.x * 32 + (w & 1) * 16;
    int colb = (w >> 1) * 64;
    int r = l & 15, kg = l >> 4;            // row/col in frag, k-group
    int row = brow + r; if (row >= N) row = N - 1;
    const float*  xp = X  + (size_t)row * F_IN + kg * 8;
    const ushort* wp = WT + (size_t)(colb + r) * F_IN + kg * 8;
    f32x4 acc[4] = {};
    for (int k0 = 0; k0 < F_IN; k0 += 32) {
        float4 xa = *(const float4*)(xp + k0);
        float4 xb = *(const float4*)(xp + k0 + 4);
        union { short8 v; ushort u[8]; } A;
        A.u[0] = f2bf(xa.x); A.u[1] = f2bf(xa.y); A.u[2] = f2bf(xa.z); A.u[3] = f2bf(xa.w);
        A.u[4] = f2bf(xb.x); A.u[5] = f2bf(xb.y); A.u[6] = f2bf(xb.z); A.u[7] = f2bf(xb.w);
        #pragma unroll
        for (int f = 0; f < 4; ++f) {
            short8 B = *(const short8*)(wp + (size_t)f * 16 * F_IN + k0);
            acc[f] = __builtin_amdgcn_mfma_f32_16x16x32_bf16(A.v, B, acc[f], 0, 0, 0);
        }
    }
    #pragma unroll
    for (int f = 0; f < 4; ++f) {
        #pragma unroll
        for (int rr = 0; rr < 4; ++rr) {
            int orow = brow + kg * 4 + rr;          // D: col=lane&15, row=(lane>>4)*4+reg
            int ocol = colb + f * 16 + r;
            if (orow < N) H[(size_t)orow * F_H + ocol] = f2bf(acc[f][rr]);
        }
    }
}

// ---------------- agg1 + relu + dot(w2v) -> g ----------------
// one wave per node; lane holds 2 bf16 features; 4-edge unroll for MLP

__global__ __launch_bounds__(256) void agg1_g_kernel(
        const ushort* __restrict__ H, const int* __restrict__ offs,
        const int2* __restrict__ csr, const float* __restrict__ dinv,
        const float* __restrict__ b1, const float* __restrict__ w2v,
        float* __restrict__ g, int N) {
    int gw = (int)((blockIdx.x * blockDim.x + threadIdx.x) >> 6);
    int lane = threadIdx.x & 63;
    if (gw >= N) return;
    float di = dinv[gw];
    float sw = di * di;
    uint hv = *(const uint*)(H + (size_t)gw * F_H + lane * 2);
    float ax = bflo(hv) * sw, ay = bfhi(hv) * sw;
    int s = offs[gw], e = offs[gw + 1];
    int i = s;
    for (; i + 4 <= e; i += 4) {
        int2 e0 = csr[i], e1 = csr[i + 1], e2 = csr[i + 2], e3 = csr[i + 3];
        uint v0 = *(const uint*)(H + (size_t)e0.x * F_H + lane * 2);
        uint v1 = *(const uint*)(H + (size_t)e1.x * F_H + lane * 2);
        uint v2 = *(const uint*)(H + (size_t)e2.x * F_H + lane * 2);
        uint v3 = *(const uint*)(H + (size_t)e3.x * F_H + lane * 2);
        float n0 = __int_as_float(e0.y), n1 = __int_as_float(e1.y);
        float n2 = __int_as_float(e2.y), n3 = __int_as_float(e3.y);
        ax = fmaf(bflo(v0), n0, ax); ay = fmaf(bfhi(v0), n0, ay);
        ax = fmaf(bflo(v1), n1, ax); ay = fmaf(bfhi(v1), n1, ay);
        ax = fmaf(bflo(v2), n2, ax); ay = fmaf(bfhi(v2), n2, ay);
        ax = fmaf(bflo(v3), n3, ax); ay = fmaf(bfhi(v3), n3, ay);
    }
    for (; i < e; ++i) {
        int2 e0 = csr[i];
        uint v0 = *(const uint*)(H + (size_t)e0.x * F_H + lane * 2);
        float n0 = __int_as_float(e0.y);
        ax = fmaf(bflo(v0), n0, ax); ay = fmaf(bfhi(v0), n0, ay);
    }
    float2 bv = *(const float2*)(b1 + lane * 2);
    ax = fmaxf(ax + bv.x, 0.0f);
    ay = fmaxf(ay + bv.y, 0.0f);
    float2 wv = *(const float2*)(w2v + lane * 2);
    float v = fmaf(ax, wv.x, ay * wv.y);
    #pragma unroll
    for (int off = 32; off; off >>= 1) v += __shfl_xor(v, off, 64);
    if (lane == 0) g[gw] = v;
}

// ---------------- scalar aggregation: hw[n] ----------------

__global__ void agg_s_kernel(const float* __restrict__ g, const int* __restrict__ offs,
                             const int2* __restrict__ csr, const float* __restrict__ dinv,
                             float* __restrict__ hw, int N) {
    int i = blockIdx.x * blockDim.x + threadIdx.x;
    if (i >= N) return;
    float di = dinv[i];
    float acc = g[i] * di * di;
    int s = offs[i], e = offs[i + 1];
    int j = s;
    for (; j + 4 <= e; j += 4) {
        int2 a = csr[j], b = csr[j + 1], c = csr[j + 2], d = csr[j + 3];
        float g0 = g[a.x], g1 = g[b.x], g2 = g[c.x], g3 = g[d.x];
        acc = fmaf(__int_as_float(a.y), g0, acc);
        acc = fmaf(__int_as_float(b.y), g1, acc);
        acc = fmaf(__int_as_float(c.y), g2, acc);
        acc = fmaf(__int_as_float(d.y), g3, acc);
    }
    for (; j < e; ++j) {
        int2 a = csr[j];
        acc = fmaf(__int_as_float(a.y), g[a.x], acc);
    }
    hw[i] = acc;
}

// ---------------- per-edge scoring ----------------

__global__ __launch_bounds__(256) void score_kernel(
        const float* __restrict__ hw, const int* __restrict__ pos_ei,
        const int* __restrict__ neg_ei, int Ep, const float* __restrict__ score_b,
        float* __restrict__ out, float* __restrict__ partials) {
    __shared__ float sdata[256];
    int Etot = 2 * Ep;
    int idx = blockIdx.x * 256 + threadIdx.x;
    float local = 0.0f;
    if (idx < Etot) {
        int src, dst;
        if (idx < Ep) { src = pos_ei[idx];       dst = pos_ei[Ep + idx]; }
        else          { int e = idx - Ep; src = neg_ei[e]; dst = neg_ei[Ep + e]; }
        float s = hw[src] - hw[dst];
        out[idx] = fmaxf(s + score_b[0], 0.0f);
        local = s;
    }
    sdata[threadIdx.x] = local;
    __syncthreads();
    for (int d = 128; d; d >>= 1) {
        if ((int)threadIdx.x < d) sdata[threadIdx.x] += sdata[threadIdx.x + d];
        __syncthreads();
    }
    if (threadIdx.x == 0) partials[blockIdx.x] = sdata[0];
}

__global__ void loss_final_kernel(const float* __restrict__ partials, int n,
                                  float* __restrict__ loss_out, float inv) {
    __shared__ float sdata[256];
    float local = 0.0f;
    for (int i = threadIdx.x; i < n; i += 256) local += partials[i];
    sdata[threadIdx.x] = local;
    __syncthreads();
    for (int d = 128; d; d >>= 1) {
        if ((int)threadIdx.x < d) sdata[threadIdx.x] += sdata[threadIdx.x + d];
        __syncthreads();
    }
    if (threadIdx.x == 0) *loss_out = sdata[0] * inv;
}

// ---------------- launch ----------------

extern "C" void kernel_launch(void* const* d_in, const int* in_sizes, int n_in,
                              void* d_out, int out_size, void* d_ws, size_t ws_size,
                              hipStream_t stream) {
    const float* x        = (const float*)d_in[0];
    const int*   edge     = (const int*)d_in[1];
    const int*   pos_ei   = (const int*)d_in[2];
    const int*   neg_ei   = (const int*)d_in[3];
    const float* W1       = (const float*)d_in[4];
    const float* b1       = (const float*)d_in[5];
    const float* W2       = (const float*)d_in[6];
    const float* score_w  = (const float*)d_in[8];
    const float* score_b  = (const float*)d_in[9];

    int N    = in_sizes[0] / F_IN;   // 100000
    int E    = in_sizes[1] / 2;      // 3.2M
    int Ep   = in_sizes[2] / 2;      // 500k
    int Etot = 2 * Ep;               // 1M
    float* out = (float*)d_out;      // [Etot] scores then [1] loss

    int nb = (N + 1023) / 1024;      // scan blocks

    // workspace carve (256B aligned)
    char* p = (char*)d_ws;
    auto alloc = [&](size_t bytes) { char* r = p; p += (bytes + 255) & ~(size_t)255; return r; };
    int*    cnt      = (int*)   alloc((size_t)N * 4);
    int*    offs     = (int*)   alloc((size_t)(N + 1) * 4);
    int*    cursor   = (int*)   alloc((size_t)N * 4);
    int*    bsum     = (int*)   alloc((size_t)nb * 4);
    float*  dinv     = (float*) alloc((size_t)N * 4);
    float*  gbuf     = (float*) alloc((size_t)N * 4);
    float*  hw       = (float*) alloc((size_t)N * 4);
    float*  w2v      = (float*) alloc(F_H * 4);
    ushort* WT       = (ushort*)alloc((size_t)F_IN * F_H * 2);
    int2*   csr      = (int2*)  alloc((size_t)E * 8);
    ushort* h1       = (ushort*)alloc((size_t)N * F_H * 2);
    int sblk = (Etot + 255) / 256;
    float*  partials = (float*) alloc((size_t)sblk * 4);

    hipMemsetAsync(cnt, 0, (size_t)N * 4, stream);
    count_kernel<<<2048, 256, 0, stream>>>(edge + E, E, cnt);
    dinv_kernel<<<(N + 255) / 256, 256, 0, stream>>>(cnt, dinv, N);
    bsum_kernel<<<nb, 1024, 0, stream>>>(cnt, bsum, N);
    bscan_kernel<<<1, 64, 0, stream>>>(bsum, nb);
    offs_kernel<<<nb, 1024, 0, stream>>>(cnt, bsum, offs, cursor, N);
    fill_kernel<<<2048, 256, 0, stream>>>(edge, E, cursor, dinv, csr);
    w2v_kernel<<<1, 128, 0, stream>>>(W2, score_w, w2v);
    wt_kernel<<<(F_IN * F_H + 255) / 256, 256, 0, stream>>>(W1, WT);
    gemm1_mfma<<<(N + 31) / 32, 256, 0, stream>>>(x, WT, h1, N);
    agg1_g_kernel<<<(N * 64 + 255) / 256, 256, 0, stream>>>(h1, offs, csr, dinv, b1,
                                                            w2v, gbuf, N);
    agg_s_kernel<<<(N + 255) / 256, 256, 0, stream>>>(gbuf, offs, csr, dinv, hw, N);
    score_kernel<<<sblk, 256, 0, stream>>>(hw, pos_ei, neg_ei, Ep, score_b, out, partials);
    loss_final_kernel<<<1, 256, 0, stream>>>(partials, sblk, out + Etot, 1.0f / (float)Etot);
}

// Round 4
// 775.518 us; speedup vs baseline: 1.6854x; 1.0852x over previous
//
#include <hip/hip_runtime.h>
#include <hip/hip_bf16.h>

// GCN link-prediction net, algebraically collapsed:
//   h1 = x @ W1                  (bf16 MFMA, fp32 accum, LDS-staged B)
//   g[n] = relu(agg(h1)[n] + b1) . (W2 @ score_w)   (layer2 GEMM eliminated)
//   hw[n] = scalar-agg(g)        (b2 cancels in dist = h[j]-h[i])
//   out[e] = relu(hw[src]-hw[dst] + sb); loss = mean(hw[src]-hw[dst])

#define F_IN 512
#define F_H  128
#define F_C  64

typedef __attribute__((ext_vector_type(8))) short short8;
typedef __attribute__((ext_vector_type(4))) float f32x4;

__device__ __forceinline__ ushort f2bf(float f) {
    uint u = __float_as_uint(f);
    uint r = (u + 0x7fffu + ((u >> 16) & 1u)) >> 16;   // RNE
    return (ushort)r;
}
__device__ __forceinline__ float bflo(uint v) { return __uint_as_float(v << 16); }
__device__ __forceinline__ float bfhi(uint v) { return __uint_as_float(v & 0xffff0000u); }

__device__ __forceinline__ void gload_lds16(const void* g, void* l) {
    __builtin_amdgcn_global_load_lds(
        (const __attribute__((address_space(1))) void*)g,
        (__attribute__((address_space(3))) void*)l, 16, 0, 0);
}

// ---------------- CSR build ----------------

__global__ void count_kernel(const int* __restrict__ col, int E, int* __restrict__ cnt) {
    int stride = gridDim.x * blockDim.x;
    for (int e = blockIdx.x * blockDim.x + threadIdx.x; e < E; e += stride)
        atomicAdd(&cnt[col[e]], 1);
}

__global__ void dinv_kernel(const int* __restrict__ cnt, float* __restrict__ dinv, int N) {
    int i = blockIdx.x * blockDim.x + threadIdx.x;
    if (i < N) {
        float deg = (float)cnt[i] + 1.0f;   // +1 self loop
        dinv[i] = 1.0f / sqrtf(deg);
    }
}

// hierarchical scan: per-block sums -> tiny serial scan -> per-block scan
__global__ __launch_bounds__(1024) void bsum_kernel(const int* __restrict__ cnt,
                                                    int* __restrict__ bsum, int N) {
    __shared__ int sm[1024];
    int i = blockIdx.x * 1024 + threadIdx.x;
    sm[threadIdx.x] = (i < N) ? cnt[i] : 0;
    __syncthreads();
    for (int d = 512; d; d >>= 1) {
        if ((int)threadIdx.x < d) sm[threadIdx.x] += sm[threadIdx.x + d];
        __syncthreads();
    }
    if (threadIdx.x == 0) bsum[blockIdx.x] = sm[0];
}

__global__ void bscan_kernel(int* __restrict__ bsum, int nb) {
    if (threadIdx.x == 0 && blockIdx.x == 0) {
        int run = 0;
        for (int b = 0; b < nb; ++b) { int v = bsum[b]; bsum[b] = run; run += v; }
    }
}

__global__ __launch_bounds__(1024) void offs_kernel(const int* __restrict__ cnt,
                                                    const int* __restrict__ boffs,
                                                    int* __restrict__ offs,
                                                    int* __restrict__ cursor, int N) {
    __shared__ int sm[1024];
    int i = blockIdx.x * 1024 + threadIdx.x;
    int v = (i < N) ? cnt[i] : 0;
    sm[threadIdx.x] = v;
    __syncthreads();
    for (int d = 1; d < 1024; d <<= 1) {
        int t = ((int)threadIdx.x >= d) ? sm[threadIdx.x - d] : 0;
        __syncthreads();
        sm[threadIdx.x] += t;
        __syncthreads();
    }
    int incl = sm[threadIdx.x];
    int base = boffs[blockIdx.x];
    if (i < N) {
        int ex = base + incl - v;
        offs[i] = ex; cursor[i] = ex;
        if (i == N - 1) offs[N] = base + incl;
    }
}

__global__ void fill_kernel(const int* __restrict__ ei, int E, int* __restrict__ cursor,
                            const float* __restrict__ dinv, int2* __restrict__ csr) {
    int stride = gridDim.x * blockDim.x;
    for (int e = blockIdx.x * blockDim.x + threadIdx.x; e < E; e += stride) {
        int r = ei[e];          // source
        int c = ei[E + e];      // target
        int idx = atomicAdd(&cursor[c], 1);
        int2 v; v.x = r; v.y = __float_as_int(dinv[r] * dinv[c]);
        csr[idx] = v;
    }
}

// ---------------- tiny weight prep ----------------

__global__ void w2v_kernel(const float* __restrict__ W2, const float* __restrict__ sw,
                           float* __restrict__ w2v) {
    int k = threadIdx.x;
    if (k < F_H) {
        float acc = 0.0f;
        #pragma unroll
        for (int c = 0; c < F_C; ++c) acc += W2[k * F_C + c] * sw[c];
        w2v[k] = acc;
    }
}

// W_T[c][k] = bf16(W1[k][c])
__global__ void wt_kernel(const float* __restrict__ W, ushort* __restrict__ WT) {
    int i = blockIdx.x * 256 + threadIdx.x;
    if (i < F_IN * F_H) {
        int k = i >> 7, c = i & 127;
        WT[c * F_IN + k] = f2bf(W[i]);
    }
}

// ---------------- GEMM1 via MFMA: H[N,128] (bf16) = X[N,512] @ W1 ----------------
// block = 256 = 4 waves; tile 64 rows x 128 cols; wave w owns rows w*16..w*16+15, ALL cols.
// B[128 cols][64 k] staged per k-tile in LDS via global_load_lds with XOR-swizzled source.

__global__ __launch_bounds__(256) void gemm1_mfma(const float* __restrict__ X,
                                                  const ushort* __restrict__ WT,
                                                  ushort* __restrict__ H, int N) {
    __shared__ ushort Bl[128 * 64];   // 16 KB, [col][phys-chunk] 16B chunks, XOR-swizzled
    int tid = threadIdx.x;
    int w = tid >> 6, l = tid & 63;
    int r = l & 15, kg = l >> 4;
    int brow = blockIdx.x * 64 + w * 16;
    int row = brow + r; if (row >= N) row = N - 1;
    const float* xp = X + (size_t)row * F_IN + kg * 8;
    f32x4 acc[8] = {};

    for (int t = 0; t < 8; ++t) {
        int k0 = t * 64;
        // A loads for this tile (2 k-steps of 32): issue early
        float4 xa0 = *(const float4*)(xp + k0);
        float4 xa1 = *(const float4*)(xp + k0 + 4);
        float4 xb0 = *(const float4*)(xp + k0 + 32);
        float4 xb1 = *(const float4*)(xp + k0 + 36);
        __syncthreads();                    // previous tile's B readers done
        // stage B tile: 1024 chunks of 16B; wave w stages chunks (w*4+j)*64 + lane
        #pragma unroll
        for (int j = 0; j < 4; ++j) {
            int chunk = (w * 4 + j) * 64 + l;
            int col = chunk >> 3, ph = chunk & 7;
            const ushort* src = WT + (size_t)col * F_IN + k0 + ((ph ^ (col & 7)) << 3);
            gload_lds16(src, (char*)Bl + (size_t)(w * 4 + j) * 1024);
        }
        __syncthreads();                    // drains vmcnt -> B in LDS, A in regs
        union { short8 v; ushort u[8]; } A0, A1;
        A0.u[0] = f2bf(xa0.x); A0.u[1] = f2bf(xa0.y); A0.u[2] = f2bf(xa0.z); A0.u[3] = f2bf(xa0.w);
        A0.u[4] = f2bf(xa1.x); A0.u[5] = f2bf(xa1.y); A0.u[6] = f2bf(xa1.z); A0.u[7] = f2bf(xa1.w);
        A1.u[0] = f2bf(xb0.x); A1.u[1] = f2bf(xb0.y); A1.u[2] = f2bf(xb0.z); A1.u[3] = f2bf(xb0.w);
        A1.u[4] = f2bf(xb1.x); A1.u[5] = f2bf(xb1.y); A1.u[6] = f2bf(xb1.z); A1.u[7] = f2bf(xb1.w);
        #pragma unroll
        for (int f = 0; f < 8; ++f) {
            int col = f * 16 + r;
            short8 B0 = *(const short8*)((const char*)Bl + col * 128 + ((kg ^ (r & 7)) << 4));
            acc[f] = __builtin_amdgcn_mfma_f32_16x16x32_bf16(A0.v, B0, acc[f], 0, 0, 0);
        }
        #pragma unroll
        for (int f = 0; f < 8; ++f) {
            int col = f * 16 + r;
            short8 B1 = *(const short8*)((const char*)Bl + col * 128 + (((4 + kg) ^ (r & 7)) << 4));
            acc[f] = __builtin_amdgcn_mfma_f32_16x16x32_bf16(A1.v, B1, acc[f], 0, 0, 0);
        }
    }
    // D: col = lane&15, row = (lane>>4)*4 + reg
    #pragma unroll
    for (int f = 0; f < 8; ++f) {
        #pragma unroll
        for (int rr = 0; rr < 4; ++rr) {
            int orow = brow + kg * 4 + rr;
            if (orow < N) H[(size_t)orow * F_H + f * 16 + r] = f2bf(acc[f][rr]);
        }
    }
}

// ---------------- agg1 + relu + dot(w2v) -> g ----------------
// one wave per node; 16 lanes per edge (lane loads uint4 = 8 bf16 = 16B of the 256B row);
// 4 edges per iteration x unroll 2 = 8 gathers in flight.

__global__ __launch_bounds__(256) void agg1_g_kernel(
        const ushort* __restrict__ H, const int* __restrict__ offs,
        const int2* __restrict__ csr, const float* __restrict__ dinv,
        const float* __restrict__ b1, const float* __restrict__ w2v,
        float* __restrict__ g, int N) {
    int gw = (int)((blockIdx.x * blockDim.x + threadIdx.x) >> 6);
    if (gw >= N) return;
    int lane = threadIdx.x & 63;
    int q = lane >> 4, fr = lane & 15;
    size_t fb = (size_t)fr * 16;          // byte offset within a 256B row
    float acc[8] = {};
    float di = dinv[gw];
    float sw = di * di;
    if (q == 0) {
        uint4 u = *(const uint4*)((const char*)H + (size_t)gw * 256 + fb);
        acc[0] = bflo(u.x) * sw; acc[1] = bfhi(u.x) * sw;
        acc[2] = bflo(u.y) * sw; acc[3] = bfhi(u.y) * sw;
        acc[4] = bflo(u.z) * sw; acc[5] = bfhi(u.z) * sw;
        acc[6] = bflo(u.w) * sw; acc[7] = bfhi(u.w) * sw;
    }
    int s = offs[gw], e = offs[gw + 1];
    int i = s;
    for (; i + 8 <= e; i += 8) {
        int2 c0 = csr[i + q];
        int2 c1 = csr[i + 4 + q];
        uint4 u0 = *(const uint4*)((const char*)H + (size_t)c0.x * 256 + fb);
        uint4 u1 = *(const uint4*)((const char*)H + (size_t)c1.x * 256 + fb);
        float n0 = __int_as_float(c0.y), n1 = __int_as_float(c1.y);
        acc[0] = fmaf(bflo(u0.x), n0, acc[0]); acc[1] = fmaf(bfhi(u0.x), n0, acc[1]);
        acc[2] = fmaf(bflo(u0.y), n0, acc[2]); acc[3] = fmaf(bfhi(u0.y), n0, acc[3]);
        acc[4] = fmaf(bflo(u0.z), n0, acc[4]); acc[5] = fmaf(bfhi(u0.z), n0, acc[5]);
        acc[6] = fmaf(bflo(u0.w), n0, acc[6]); acc[7] = fmaf(bfhi(u0.w), n0, acc[7]);
        acc[0] = fmaf(bflo(u1.x), n1, acc[0]); acc[1] = fmaf(bfhi(u1.x), n1, acc[1]);
        acc[2] = fmaf(bflo(u1.y), n1, acc[2]); acc[3] = fmaf(bfhi(u1.y), n1, acc[3]);
        acc[4] = fmaf(bflo(u1.z), n1, acc[4]); acc[5] = fmaf(bfhi(u1.z), n1, acc[5]);
        acc[6] = fmaf(bflo(u1.w), n1, acc[6]); acc[7] = fmaf(bfhi(u1.w), n1, acc[7]);
    }
    for (; i + 4 <= e; i += 4) {
        int2 c0 = csr[i + q];
        uint4 u0 = *(const uint4*)((const char*)H + (size_t)c0.x * 256 + fb);
        float n0 = __int_as_float(c0.y);
        acc[0] = fmaf(bflo(u0.x), n0, acc[0]); acc[1] = fmaf(bfhi(u0.x), n0, acc[1]);
        acc[2] = fmaf(bflo(u0.y), n0, acc[2]); acc[3] = fmaf(bfhi(u0.y), n0, acc[3]);
        acc[4] = fmaf(bflo(u0.z), n0, acc[4]); acc[5] = fmaf(bfhi(u0.z), n0, acc[5]);
        acc[6] = fmaf(bflo(u0.w), n0, acc[6]); acc[7] = fmaf(bfhi(u0.w), n0, acc[7]);
    }
    int rem = e - i;
    if (q < rem) {
        int2 c0 = csr[i + q];
        uint4 u0 = *(const uint4*)((const char*)H + (size_t)c0.x * 256 + fb);
        float n0 = __int_as_float(c0.y);
        acc[0] = fmaf(bflo(u0.x), n0, acc[0]); acc[1] = fmaf(bfhi(u0.x), n0, acc[1]);
        acc[2] = fmaf(bflo(u0.y), n0, acc[2]); acc[3] = fmaf(bfhi(u0.y), n0, acc[3]);
        acc[4] = fmaf(bflo(u0.z), n0, acc[4]); acc[5] = fmaf(bfhi(u0.z), n0, acc[5]);
        acc[6] = fmaf(bflo(u0.w), n0, acc[6]); acc[7] = fmaf(bfhi(u0.w), n0, acc[7]);
    }
    // combine the 4 quarter-wave partial sums
    #pragma unroll
    for (int f = 0; f < 8; ++f) {
        acc[f] += __shfl_xor(acc[f], 16, 64);
        acc[f] += __shfl_xor(acc[f], 32, 64);
    }
    float4 bv0 = *(const float4*)(b1 + fr * 8);
    float4 bv1 = *(const float4*)(b1 + fr * 8 + 4);
    float4 wv0 = *(const float4*)(w2v + fr * 8);
    float4 wv1 = *(const float4*)(w2v + fr * 8 + 4);
    float v = fmaxf(acc[0] + bv0.x, 0.0f) * wv0.x;
    v = fmaf(fmaxf(acc[1] + bv0.y, 0.0f), wv0.y, v);
    v = fmaf(fmaxf(acc[2] + bv0.z, 0.0f), wv0.z, v);
    v = fmaf(fmaxf(acc[3] + bv0.w, 0.0f), wv0.w, v);
    v = fmaf(fmaxf(acc[4] + bv1.x, 0.0f), wv1.x, v);
    v = fmaf(fmaxf(acc[5] + bv1.y, 0.0f), wv1.y, v);
    v = fmaf(fmaxf(acc[6] + bv1.z, 0.0f), wv1.z, v);
    v = fmaf(fmaxf(acc[7] + bv1.w, 0.0f), wv1.w, v);
    v += __shfl_xor(v, 1, 64);
    v += __shfl_xor(v, 2, 64);
    v += __shfl_xor(v, 4, 64);
    v += __shfl_xor(v, 8, 64);
    if (lane == 0) g[gw] = v;
}

// ---------------- scalar aggregation: hw[n] ----------------

__global__ void agg_s_kernel(const float* __restrict__ g, const int* __restrict__ offs,
                             const int2* __restrict__ csr, const float* __restrict__ dinv,
                             float* __restrict__ hw, int N) {
    int i = blockIdx.x * blockDim.x + threadIdx.x;
    if (i >= N) return;
    float di = dinv[i];
    float acc = g[i] * di * di;
    int s = offs[i], e = offs[i + 1];
    int j = s;
    for (; j + 4 <= e; j += 4) {
        int2 a = csr[j], b = csr[j + 1], c = csr[j + 2], d = csr[j + 3];
        float g0 = g[a.x], g1 = g[b.x], g2 = g[c.x], g3 = g[d.x];
        acc = fmaf(__int_as_float(a.y), g0, acc);
        acc = fmaf(__int_as_float(b.y), g1, acc);
        acc = fmaf(__int_as_float(c.y), g2, acc);
        acc = fmaf(__int_as_float(d.y), g3, acc);
    }
    for (; j < e; ++j) {
        int2 a = csr[j];
        acc = fmaf(__int_as_float(a.y), g[a.x], acc);
    }
    hw[i] = acc;
}

// ---------------- per-edge scoring ----------------

__global__ __launch_bounds__(256) void score_kernel(
        const float* __restrict__ hw, const int* __restrict__ pos_ei,
        const int* __restrict__ neg_ei, int Ep, const float* __restrict__ score_b,
        float* __restrict__ out, float* __restrict__ partials) {
    __shared__ float sdata[256];
    int Etot = 2 * Ep;
    int idx = blockIdx.x * 256 + threadIdx.x;
    float local = 0.0f;
    if (idx < Etot) {
        int src, dst;
        if (idx < Ep) { src = pos_ei[idx];       dst = pos_ei[Ep + idx]; }
        else          { int e = idx - Ep; src = neg_ei[e]; dst = neg_ei[Ep + e]; }
        float s = hw[src] - hw[dst];
        out[idx] = fmaxf(s + score_b[0], 0.0f);
        local = s;
    }
    sdata[threadIdx.x] = local;
    __syncthreads();
    for (int d = 128; d; d >>= 1) {
        if ((int)threadIdx.x < d) sdata[threadIdx.x] += sdata[threadIdx.x + d];
        __syncthreads();
    }
    if (threadIdx.x == 0) partials[blockIdx.x] = sdata[0];
}

__global__ void loss_final_kernel(const float* __restrict__ partials, int n,
                                  float* __restrict__ loss_out, float inv) {
    __shared__ float sdata[256];
    float local = 0.0f;
    for (int i = threadIdx.x; i < n; i += 256) local += partials[i];
    sdata[threadIdx.x] = local;
    __syncthreads();
    for (int d = 128; d; d >>= 1) {
        if ((int)threadIdx.x < d) sdata[threadIdx.x] += sdata[threadIdx.x + d];
        __syncthreads();
    }
    if (threadIdx.x == 0) *loss_out = sdata[0] * inv;
}

// ---------------- launch ----------------

extern "C" void kernel_launch(void* const* d_in, const int* in_sizes, int n_in,
                              void* d_out, int out_size, void* d_ws, size_t ws_size,
                              hipStream_t stream) {
    const float* x        = (const float*)d_in[0];
    const int*   edge     = (const int*)d_in[1];
    const int*   pos_ei   = (const int*)d_in[2];
    const int*   neg_ei   = (const int*)d_in[3];
    const float* W1       = (const float*)d_in[4];
    const float* b1       = (const float*)d_in[5];
    const float* W2       = (const float*)d_in[6];
    const float* score_w  = (const float*)d_in[8];
    const float* score_b  = (const float*)d_in[9];

    int N    = in_sizes[0] / F_IN;   // 100000
    int E    = in_sizes[1] / 2;      // 3.2M
    int Ep   = in_sizes[2] / 2;      // 500k
    int Etot = 2 * Ep;               // 1M
    float* out = (float*)d_out;      // [Etot] scores then [1] loss

    int nb = (N + 1023) / 1024;      // scan blocks

    // workspace carve (256B aligned)
    char* p = (char*)d_ws;
    auto alloc = [&](size_t bytes) { char* r = p; p += (bytes + 255) & ~(size_t)255; return r; };
    int*    cnt      = (int*)   alloc((size_t)N * 4);
    int*    offs     = (int*)   alloc((size_t)(N + 1) * 4);
    int*    cursor   = (int*)   alloc((size_t)N * 4);
    int*    bsum     = (int*)   alloc((size_t)nb * 4);
    float*  dinv     = (float*) alloc((size_t)N * 4);
    float*  gbuf     = (float*) alloc((size_t)N * 4);
    float*  hw       = (float*) alloc((size_t)N * 4);
    float*  w2v      = (float*) alloc(F_H * 4);
    ushort* WT       = (ushort*)alloc((size_t)F_IN * F_H * 2);
    int2*   csr      = (int2*)  alloc((size_t)E * 8);
    ushort* h1       = (ushort*)alloc((size_t)N * F_H * 2);
    int sblk = (Etot + 255) / 256;
    float*  partials = (float*) alloc((size_t)sblk * 4);

    hipMemsetAsync(cnt, 0, (size_t)N * 4, stream);
    count_kernel<<<2048, 256, 0, stream>>>(edge + E, E, cnt);
    dinv_kernel<<<(N + 255) / 256, 256, 0, stream>>>(cnt, dinv, N);
    bsum_kernel<<<nb, 1024, 0, stream>>>(cnt, bsum, N);
    bscan_kernel<<<1, 64, 0, stream>>>(bsum, nb);
    offs_kernel<<<nb, 1024, 0, stream>>>(cnt, bsum, offs, cursor, N);
    fill_kernel<<<2048, 256, 0, stream>>>(edge, E, cursor, dinv, csr);
    w2v_kernel<<<1, 128, 0, stream>>>(W2, score_w, w2v);
    wt_kernel<<<(F_IN * F_H + 255) / 256, 256, 0, stream>>>(W1, WT);
    gemm1_mfma<<<(N + 63) / 64, 256, 0, stream>>>(x, WT, h1, N);
    agg1_g_kernel<<<(N * 64 + 255) / 256, 256, 0, stream>>>(h1, offs, csr, dinv, b1,
                                                            w2v, gbuf, N);
    agg_s_kernel<<<(N + 255) / 256, 256, 0, stream>>>(gbuf, offs, csr, dinv, hw, N);
    score_kernel<<<sblk, 256, 0, stream>>>(hw, pos_ei, neg_ei, Ep, score_b, out, partials);
    loss_final_kernel<<<1, 256, 0, stream>>>(partials, sblk, out + Etot, 1.0f / (float)Etot);
}